// Round 9
// baseline (148.227 us; speedup 1.0000x reference)
//
#include <hip/hip_runtime.h>
#include <hip/hip_bf16.h>
#include <math.h>

// Dims: B=8, T=1048576, V=257, E=8, C=128, K=512, S=512, N=64
// GEMM view: M=16384, Kdim=4096, Ncols=256.
// R9 = R8 with (1) the spill actually fixed: __launch_bounds__(256,3) ->
// 170-VGPR cap vs ~155 demand (R8's (256,4) cap=128 incl. 64 acc AGPRs ->
// scratch spill, WRITE_SIZE 24.5MB, L2 thrash); (2) vmcnt queue hygiene:
// bb[] 2-deep preloaded one t ahead (L2 ~220cyc covered by ~450cyc/t), and
// xb[] 2-deep with next-ss x16 loads issued at t==5, ~900cyc (2 t-iters)
// before any dependent wait -> B-loads never transitively wait on the HBM
// x stream (the R4 failure mode, present in diluted form in every round).
// Skeleton unchanged: 256-thr blocks = 4 waves sharing one 64x64 tile,
// 4-way K-split, B L2-direct from Wp, A gathered from 4KB embl LDS,
// LDS merge + in-register gate/patch-max epilogue. Grid 1024, 12 waves/CU.

typedef __bf16 bf16x8 __attribute__((ext_vector_type(8)));
typedef float  f32x4  __attribute__((ext_vector_type(4)));

// ---------------- ws layout ----------------
// [0, 2MB)      : Wp bf16 [nt=4][s'=16][t=8][q=4][n=64][e=8]
// [2MB, +8KB)   : emb bf16 [257][8]
// [4MB, +16.8MB): x16 ushort [16384][512]
#define WS_WP_OFF   0
#define WS_EMB_OFF  (2u << 20)
#define WS_X16_OFF  (4u << 20)

// ---------------------------------------------------------------------------
// prep: weight pack (bid<128), emb bf16 (bid==128), x->ushort (bid>=129).
// ---------------------------------------------------------------------------
__global__ void prep_kernel(const int* __restrict__ x,
                            const float* __restrict__ w1,
                            const float* __restrict__ w2,
                            const float* __restrict__ emb,
                            uint4* __restrict__ Wp4,
                            __bf16* __restrict__ embp,
                            unsigned short* __restrict__ x16) {
    int bid = blockIdx.x;
    int tid = threadIdx.x;
    if (bid < 128) {
        __shared__ __bf16 lds[8192];   // [(q*8+t)*32 + cl]*8 + e
        int cb = bid & 7;
        int sB = bid >> 3;
        int nt = cb >> 1, nhalf = cb & 1;
        const float* wsrc = (nhalf ? w2 : w1) + ((size_t)(nt << 5) << 12);
        int j4  = tid & 7;
        int pr0 = tid >> 3;
#pragma unroll
        for (int p = 0; p < 8; ++p) {
            int pair = p * 32 + pr0;          // 0..255 = (cl, e)
            int cl = pair >> 3, e = pair & 7;
            const float4 v = *(const float4*)(wsrc + ((size_t)cl << 12) + (e << 9) + (sB << 5) + (j4 << 2));
            float vv[4] = {v.x, v.y, v.z, v.w};
#pragma unroll
            for (int jj = 0; jj < 4; ++jj) {
                int j = (j4 << 2) + jj;        // byte_local
                int qq = j >> 3, tt = j & 7;
                lds[(((qq << 3) + tt) * 32 + cl) * 8 + e] = (__bf16)vv[jj];
            }
        }
        __syncthreads();
        const uint4* l4 = (const uint4*)lds;
        int base = (nt << 15) + (sB << 11) + (nhalf << 5);   // uint4 units
#pragma unroll
        for (int it = 0; it < 4; ++it) {
            int idx = it * 256 + tid;                         // 0..1023
            int qq = idx >> 8, tt = (idx >> 5) & 7, w = idx & 31;
            Wp4[base + (tt << 8) + (qq << 6) + w] = l4[idx];
        }
    } else if (bid == 128) {
        for (int i = tid; i < 2056; i += 256) embp[i] = (__bf16)emb[i];
    } else {
        // x pack: 8M ints -> 8M ushorts. 4096 blocks x 256 thr x 8 elems.
        size_t i0 = ((size_t)(bid - 129) << 11) + ((size_t)tid << 3);
        int4 v0 = *(const int4*)(x + i0);
        int4 v1 = *(const int4*)(x + i0 + 4);
        int4 o;
        o.x = (v0.x & 0xffff) | (v0.y << 16);
        o.y = (v0.z & 0xffff) | (v0.w << 16);
        o.z = (v1.x & 0xffff) | (v1.y << 16);
        o.w = (v1.z & 0xffff) | (v1.w << 16);
        *(int4*)(x16 + i0) = o;
    }
}

// ---------------------------------------------------------------------------
// gemm+epilogue: 256 threads = 4 waves, one 64x64 tile (4rg x 4nf), wave kh
// owns K-steps [kh*4, kh*4+4) = flat g in [0,32) over (ss,t). Per t: idx
// bfe from xb (static select), gather a[4] from embl, MFMA 16 with
// bb[g&1] (preloaded at g-1); preload bb[(g+1)&1]; at t==5 issue next-ss
// xb into the other xb buffer. All arrays statically indexed (full unroll).
// End: kh>0 waves dump acc to LDS (24KB) in 2 chunks, kh=0 adds + gate +
// patch-max -> out. Grid 1024 = 256 mt x 4 nt; bid&7 = XCD.
// ---------------------------------------------------------------------------
__global__ __launch_bounds__(256, 3)
void gemm_kernel(const unsigned short* __restrict__ x16,
                 const __bf16* __restrict__ Wp,
                 const uint4* __restrict__ embp,
                 const float* __restrict__ b1,
                 const float* __restrict__ b2,
                 float* __restrict__ out) {
    __shared__ uint4 embl[257];
    __shared__ float mrg[3][32][64];   // 24KB: [kh-1][rh*16+nf*4+i][lane]

    const int tid  = threadIdx.x;
    const int kh   = tid >> 6;        // wave id = K quarter
    const int lane = tid & 63;
    const int q    = lane >> 4;
    const int nl   = lane & 15;

    for (int i = tid; i < 257; i += 256) embl[i] = embp[i];

    const int bid = blockIdx.x;
    const int mt = ((bid >> 5) << 3) | (bid & 7);   // 0..255
    const int nt = (bid >> 3) & 3;
    const int m0 = mt << 6;
    const int rA = m0 + nl;

    // per-lane flat B pointer: + gt*4096 + nf*256 per access
    const char* Bflat = (const char*)Wp + ((size_t)nt << 19) + (q << 10) + (nl << 4);
    const int sp0 = kh << 2;
    const char* Bk = Bflat + ((size_t)(sp0 << 3) << 12);   // this wave's K base

    // per-rg x row base (ushort units): row = rA + rg*16, + sp*32 + q*8
    const unsigned short* xq0 = x16 + ((size_t)rA << 9) + (q << 3) + (sp0 << 5);

    // prologue: xb for ss=0, bb for g=0
    int4 xbA[4], xbB[4];
#pragma unroll
    for (int rg = 0; rg < 4; ++rg)
        xbA[rg] = *(const int4*)(xq0 + ((size_t)rg << 13));
    bf16x8 bb[2][4];
#pragma unroll
    for (int nf = 0; nf < 4; ++nf)
        bb[0][nf] = *reinterpret_cast<const bf16x8*>(Bk + (nf << 8));

    __syncthreads();   // embl ready; no barriers in main loop

    f32x4 acc[4][4] = {};

#pragma unroll
    for (int ss = 0; ss < 4; ++ss) {
#pragma unroll
        for (int t = 0; t < 8; ++t) {
            const int g = (ss << 3) + t;
            // preload bb for g+1 (one t ahead: ~450cyc > ~220cyc L2)
            if (g < 31) {
                const char* pbn = Bk + ((size_t)(g + 1) << 12);
#pragma unroll
                for (int nf = 0; nf < 4; ++nf)
                    bb[(g + 1) & 1][nf] = *reinterpret_cast<const bf16x8*>(pbn + (nf << 8));
            }
            // issue next-ss x loads ~2 t-iters before first use
            if (t == 5 && ss < 3) {
                const unsigned short* xn = xq0 + ((ss + 1) << 5);
#pragma unroll
                for (int rg = 0; rg < 4; ++rg) {
                    if (ss & 1) xbA[rg] = *(const int4*)(xn + ((size_t)rg << 13));
                    else        xbB[rg] = *(const int4*)(xn + ((size_t)rg << 13));
                }
            }
            // A gather (idx statically selected from the active xb buffer)
            bf16x8 a[4];
#pragma unroll
            for (int rg = 0; rg < 4; ++rg) {
                int w;
                if (ss & 1) w = (t < 2) ? xbB[rg].x : (t < 4) ? xbB[rg].y : (t < 6) ? xbB[rg].z : xbB[rg].w;
                else        w = (t < 2) ? xbA[rg].x : (t < 4) ? xbA[rg].y : (t < 6) ? xbA[rg].z : xbA[rg].w;
                int idx = (t & 1) ? ((unsigned)w >> 16) : (w & 0xffff);
                a[rg] = *reinterpret_cast<const bf16x8*>(&embl[idx]);
            }
#pragma unroll
            for (int nf = 0; nf < 4; ++nf)
#pragma unroll
                for (int rg = 0; rg < 4; ++rg)
                    acc[rg][nf] = __builtin_amdgcn_mfma_f32_16x16x32_bf16(
                        a[rg], bb[g & 1][nf], acc[rg][nf], 0, 0, 0);
        }
    }

    // ---- K-quarter merge (2 chunks of 2 rg, 24KB LDS) ----
#pragma unroll
    for (int half = 0; half < 2; ++half) {
        if (kh > 0) {
#pragma unroll
            for (int rh = 0; rh < 2; ++rh)
#pragma unroll
                for (int nf = 0; nf < 4; ++nf)
#pragma unroll
                    for (int i = 0; i < 4; ++i)
                        mrg[kh - 1][(rh << 4) + (nf << 2) + i][lane] =
                            acc[(half << 1) + rh][nf][i];
        }
        __syncthreads();
        if (kh == 0) {
#pragma unroll
            for (int rh = 0; rh < 2; ++rh)
#pragma unroll
                for (int nf = 0; nf < 4; ++nf)
#pragma unroll
                    for (int i = 0; i < 4; ++i) {
                        int r = (rh << 4) + (nf << 2) + i;
                        acc[(half << 1) + rh][nf][i] +=
                            mrg[0][r][lane] + mrg[1][r][lane] + mrg[2][r][lane];
                    }
        }
        __syncthreads();
    }
    if (kh > 0) return;

    // ---- fused epilogue (kh=0 wave) ----
    // acc[rg][nf][i]: row = m0 + rg*16 + q*4 + i
    //   nf in {0,1}: c1 of channel ch = nt*32 + nf*16 + nl; nf+2: c2 same ch.
    // patch (32 rows) = mt*2 + (rg>>1); per-lane max over (rg&1, i), then
    // shfl_xor 16/32 across q-groups.
    float bb1[2], bb2[2];
#pragma unroll
    for (int nf = 0; nf < 2; ++nf) {
        int ch = (nt << 5) + (nf << 4) + nl;
        bb1[nf] = b1[ch];
        bb2[nf] = b2[ch];
    }
#pragma unroll
    for (int ph = 0; ph < 2; ++ph) {
#pragma unroll
        for (int nf = 0; nf < 2; ++nf) {
            float v = -INFINITY;
#pragma unroll
            for (int rh = 0; rh < 2; ++rh) {
                int rg = (ph << 1) + rh;
#pragma unroll
                for (int i = 0; i < 4; ++i) {
                    float c1 = acc[rg][nf][i] + bb1[nf];
                    float c2 = acc[rg][nf + 2][i] + bb2[nf];
                    float g = c1 * (1.0f / (1.0f + __expf(-c2)));
                    v = fmaxf(v, g);
                }
            }
            v = fmaxf(v, __shfl_xor(v, 16));
            v = fmaxf(v, __shfl_xor(v, 32));
            if (lane < 16) {
                int P = (mt << 1) + ph;                   // global patch id
                out[(size_t)P * 128 + (nt << 5) + (nf << 4) + nl] = v;
            }
        }
    }
}

// ---------------------------------------------------------------------------
extern "C" void kernel_launch(void* const* d_in, const int* in_sizes, int n_in,
                              void* d_out, int out_size, void* d_ws, size_t ws_size,
                              hipStream_t stream) {
    const int*   x   = (const int*)d_in[0];
    const float* emb = (const float*)d_in[1];
    const float* w1  = (const float*)d_in[2];
    const float* b1  = (const float*)d_in[3];
    const float* w2  = (const float*)d_in[4];
    const float* b2  = (const float*)d_in[5];
    float* out = (float*)d_out;

    char* ws = (char*)d_ws;
    __bf16*         Wp   = (__bf16*)(ws + WS_WP_OFF);
    __bf16*         embp = (__bf16*)(ws + WS_EMB_OFF);
    unsigned short* x16  = (unsigned short*)(ws + WS_X16_OFF);

    prep_kernel<<<129 + 4096, 256, 0, stream>>>(x, w1, w2, emb, (uint4*)Wp, embp, x16);
    gemm_kernel<<<1024, 256, 0, stream>>>(x16, Wp, (const uint4*)embp, b1, b2, out);
}

// Round 10
// 127.321 us; speedup vs baseline: 1.1642x; 1.1642x over previous
//
#include <hip/hip_runtime.h>
#include <hip/hip_bf16.h>
#include <math.h>

// Dims: B=8, T=1048576, V=257, E=8, C=128, K=512, S=512, N=64
// GEMM view: M=16384, Kdim=4096, Ncols=256.
// R10: latency model says per-wave t-iter ~1500cyc; throughput = waves/SIMD.
// R4(1/SIMD)=80us, R5/R2(2/SIMD)=51/49.5us fit exactly. This round runs the
// first clean 3/SIMD point: 256-thr blocks (4 waves = 1/SIMD each), K-split-4
// over one 64x64 tile, __launch_bounds__(256,3) -> 170-reg cap = 64 acc +
// ~100 arch (R5-proven demand, no spill). Inner loop = R5's verified pattern:
// bb 2-deep refill-AFTER-consume (2 t-iter vmcnt gap), x16 int4 ping-pong
// loaded TWO steps ahead at t==7 (9 t-iters before use; bb refills queued
// behind it are consumed >=3 t-iters later -> no transitive HBM wait, the
// R9 regression mechanism). A gathered per-t from 4KB embl LDS.
// Merge: kh>0 dump to 24KB LDS, kh=0 adds + gate + patch-max -> out.
// Grid 1024 = 256 mt x 4 nt; bid&7 = XCD.

typedef __bf16 bf16x8 __attribute__((ext_vector_type(8)));
typedef float  f32x4  __attribute__((ext_vector_type(4)));

// ---------------- ws layout ----------------
// [0, 2MB)      : Wp bf16 [nt=4][s'=16][t=8][q=4][n=64][e=8]
// [2MB, +8KB)   : emb bf16 [257][8]
// [4MB, +16.8MB): x16 ushort [16384][512]
#define WS_WP_OFF   0
#define WS_EMB_OFF  (2u << 20)
#define WS_X16_OFF  (4u << 20)

// ---------------------------------------------------------------------------
// prep: weight pack (bid<128), emb bf16 (bid==128), x->ushort (bid>=129).
// ---------------------------------------------------------------------------
__global__ void prep_kernel(const int* __restrict__ x,
                            const float* __restrict__ w1,
                            const float* __restrict__ w2,
                            const float* __restrict__ emb,
                            uint4* __restrict__ Wp4,
                            __bf16* __restrict__ embp,
                            unsigned short* __restrict__ x16) {
    int bid = blockIdx.x;
    int tid = threadIdx.x;
    if (bid < 128) {
        __shared__ __bf16 lds[8192];   // [(q*8+t)*32 + cl]*8 + e
        int cb = bid & 7;
        int sB = bid >> 3;
        int nt = cb >> 1, nhalf = cb & 1;
        const float* wsrc = (nhalf ? w2 : w1) + ((size_t)(nt << 5) << 12);
        int j4  = tid & 7;
        int pr0 = tid >> 3;
#pragma unroll
        for (int p = 0; p < 8; ++p) {
            int pair = p * 32 + pr0;          // 0..255 = (cl, e)
            int cl = pair >> 3, e = pair & 7;
            const float4 v = *(const float4*)(wsrc + ((size_t)cl << 12) + (e << 9) + (sB << 5) + (j4 << 2));
            float vv[4] = {v.x, v.y, v.z, v.w};
#pragma unroll
            for (int jj = 0; jj < 4; ++jj) {
                int j = (j4 << 2) + jj;        // byte_local
                int qq = j >> 3, tt = j & 7;
                lds[(((qq << 3) + tt) * 32 + cl) * 8 + e] = (__bf16)vv[jj];
            }
        }
        __syncthreads();
        const uint4* l4 = (const uint4*)lds;
        int base = (nt << 15) + (sB << 11) + (nhalf << 5);   // uint4 units
#pragma unroll
        for (int it = 0; it < 4; ++it) {
            int idx = it * 256 + tid;                         // 0..1023
            int qq = idx >> 8, tt = (idx >> 5) & 7, w = idx & 31;
            Wp4[base + (tt << 8) + (qq << 6) + w] = l4[idx];
        }
    } else if (bid == 128) {
        for (int i = tid; i < 2056; i += 256) embp[i] = (__bf16)emb[i];
    } else {
        // x pack: 8M ints -> 8M ushorts. 4096 blocks x 256 thr x 8 elems.
        size_t i0 = ((size_t)(bid - 129) << 11) + ((size_t)tid << 3);
        int4 v0 = *(const int4*)(x + i0);
        int4 v1 = *(const int4*)(x + i0 + 4);
        int4 o;
        o.x = (v0.x & 0xffff) | (v0.y << 16);
        o.y = (v0.z & 0xffff) | (v0.w << 16);
        o.z = (v1.x & 0xffff) | (v1.y << 16);
        o.w = (v1.z & 0xffff) | (v1.w << 16);
        *(int4*)(x16 + i0) = o;
    }
}

// ---------------------------------------------------------------------------
// gemm+epilogue: 256 threads = 4 waves, one 64x64 tile (4rg x 4nf), wave kh
// owns K-steps [kh*4, kh*4+4), local g = ss*8+t in [0,32).
// Per t: extract idx from xb ping-pong (static), gather a[4] from embl,
// 16 MFMA with bb[t&1], refill bb[t&1] <- g+2; at t==7, ss<2: load x(ss+2)
// into the buffer just finished. Full static unroll (all regs static).
// ---------------------------------------------------------------------------
__global__ __launch_bounds__(256, 3)
void gemm_kernel(const unsigned short* __restrict__ x16,
                 const __bf16* __restrict__ Wp,
                 const uint4* __restrict__ embp,
                 const float* __restrict__ b1,
                 const float* __restrict__ b2,
                 float* __restrict__ out) {
    __shared__ uint4 embl[257];
    __shared__ float mrg[3][32][64];   // 24KB: [kh-1][rh*16+nf*4+i][lane]

    const int tid  = threadIdx.x;
    const int kh   = tid >> 6;        // wave id = K quarter
    const int lane = tid & 63;
    const int q    = lane >> 4;
    const int nl   = lane & 15;

    for (int i = tid; i < 257; i += 256) embl[i] = embp[i];

    const int bid = blockIdx.x;
    const int mt = ((bid >> 5) << 3) | (bid & 7);   // 0..255
    const int nt = (bid >> 3) & 3;
    const int m0 = mt << 6;
    const int rA = m0 + nl;

    // per-lane flat B pointer for this wave's K quarter: + g*4096 + nf*256
    const int sp0 = kh << 2;
    const char* Bk = (const char*)Wp + ((size_t)nt << 19) + (q << 10) + (nl << 4)
                   + ((size_t)(sp0 << 3) << 12);

    // per-rg x row base (ushort units): row = rA + rg*16; + ss*32 + q*8
    const unsigned short* xq0 = x16 + ((size_t)rA << 9) + (q << 3) + (sp0 << 5);

    // prologue: x for ss=0 (A) and ss=1 (B); bb for g=0,1
    int4 xbA[4], xbB[4];
#pragma unroll
    for (int rg = 0; rg < 4; ++rg) {
        xbA[rg] = *(const int4*)(xq0 + ((size_t)rg << 13));
        xbB[rg] = *(const int4*)(xq0 + ((size_t)rg << 13) + 32);
    }
    bf16x8 bb[2][4];
#pragma unroll
    for (int nf = 0; nf < 4; ++nf) {
        bb[0][nf] = *reinterpret_cast<const bf16x8*>(Bk + (nf << 8));
        bb[1][nf] = *reinterpret_cast<const bf16x8*>(Bk + 4096 + (nf << 8));
    }

    __syncthreads();   // embl ready; no barriers in main loop

    f32x4 acc[4][4] = {};

#pragma unroll
    for (int ss = 0; ss < 4; ++ss) {
#pragma unroll
        for (int t = 0; t < 8; ++t) {
            const int g = (ss << 3) + t;
            // A gather: idx statically selected from the active x buffer
            bf16x8 a[4];
#pragma unroll
            for (int rg = 0; rg < 4; ++rg) {
                int w;
                if (ss & 1) w = (t < 2) ? xbB[rg].x : (t < 4) ? xbB[rg].y : (t < 6) ? xbB[rg].z : xbB[rg].w;
                else        w = (t < 2) ? xbA[rg].x : (t < 4) ? xbA[rg].y : (t < 6) ? xbA[rg].z : xbA[rg].w;
                int idx = (t & 1) ? ((unsigned)w >> 16) : (w & 0xffff);
                a[rg] = *reinterpret_cast<const bf16x8*>(&embl[idx]);
            }
#pragma unroll
            for (int nf = 0; nf < 4; ++nf)
#pragma unroll
                for (int rg = 0; rg < 4; ++rg)
                    acc[rg][nf] = __builtin_amdgcn_mfma_f32_16x16x32_bf16(
                        a[rg], bb[g & 1][nf], acc[rg][nf], 0, 0, 0);
            // refill the bb slot just consumed with g+2 (2 t-iter vmcnt gap)
            {
                int g2 = (g + 2 > 31) ? 31 : g + 2;
                const char* pb = Bk + ((size_t)g2 << 12);
#pragma unroll
                for (int nf = 0; nf < 4; ++nf)
                    bb[g & 1][nf] = *reinterpret_cast<const bf16x8*>(pb + (nf << 8));
            }
            // at the end of the step, reload the just-finished x buffer with
            // ss+2 (9 t-iters ahead of use; HBM latency fully covered, and
            // later bb refills queued behind it are consumed >=3 t-iters on)
            if (t == 7 && ss < 2) {
                const unsigned short* xn = xq0 + ((ss + 2) << 5);
#pragma unroll
                for (int rg = 0; rg < 4; ++rg) {
                    if (ss & 1) xbB[rg] = *(const int4*)(xn + ((size_t)rg << 13));
                    else        xbA[rg] = *(const int4*)(xn + ((size_t)rg << 13));
                }
            }
        }
    }

    // ---- K-quarter merge (2 chunks of 2 rg, 24KB LDS) ----
#pragma unroll
    for (int half = 0; half < 2; ++half) {
        if (kh > 0) {
#pragma unroll
            for (int rh = 0; rh < 2; ++rh)
#pragma unroll
                for (int nf = 0; nf < 4; ++nf)
#pragma unroll
                    for (int i = 0; i < 4; ++i)
                        mrg[kh - 1][(rh << 4) + (nf << 2) + i][lane] =
                            acc[(half << 1) + rh][nf][i];
        }
        __syncthreads();
        if (kh == 0) {
#pragma unroll
            for (int rh = 0; rh < 2; ++rh)
#pragma unroll
                for (int nf = 0; nf < 4; ++nf)
#pragma unroll
                    for (int i = 0; i < 4; ++i) {
                        int r = (rh << 4) + (nf << 2) + i;
                        acc[(half << 1) + rh][nf][i] +=
                            mrg[0][r][lane] + mrg[1][r][lane] + mrg[2][r][lane];
                    }
        }
        __syncthreads();
    }
    if (kh > 0) return;

    // ---- fused epilogue (kh=0 wave) ----
    // acc[rg][nf][i]: row = m0 + rg*16 + q*4 + i
    //   nf in {0,1}: c1 of channel ch = nt*32 + nf*16 + nl; nf+2: c2 same ch.
    // patch (32 rows) = mt*2 + (rg>>1); per-lane max over (rg&1, i), then
    // shfl_xor 16/32 across q-groups.
    float bb1[2], bb2[2];
#pragma unroll
    for (int nf = 0; nf < 2; ++nf) {
        int ch = (nt << 5) + (nf << 4) + nl;
        bb1[nf] = b1[ch];
        bb2[nf] = b2[ch];
    }
#pragma unroll
    for (int ph = 0; ph < 2; ++ph) {
#pragma unroll
        for (int nf = 0; nf < 2; ++nf) {
            float v = -INFINITY;
#pragma unroll
            for (int rh = 0; rh < 2; ++rh) {
                int rg = (ph << 1) + rh;
#pragma unroll
                for (int i = 0; i < 4; ++i) {
                    float c1 = acc[rg][nf][i] + bb1[nf];
                    float c2 = acc[rg][nf + 2][i] + bb2[nf];
                    float g = c1 * (1.0f / (1.0f + __expf(-c2)));
                    v = fmaxf(v, g);
                }
            }
            v = fmaxf(v, __shfl_xor(v, 16));
            v = fmaxf(v, __shfl_xor(v, 32));
            if (lane < 16) {
                int P = (mt << 1) + ph;                   // global patch id
                out[(size_t)P * 128 + (nt << 5) + (nf << 4) + nl] = v;
            }
        }
    }
}

// ---------------------------------------------------------------------------
extern "C" void kernel_launch(void* const* d_in, const int* in_sizes, int n_in,
                              void* d_out, int out_size, void* d_ws, size_t ws_size,
                              hipStream_t stream) {
    const int*   x   = (const int*)d_in[0];
    const float* emb = (const float*)d_in[1];
    const float* w1  = (const float*)d_in[2];
    const float* b1  = (const float*)d_in[3];
    const float* w2  = (const float*)d_in[4];
    const float* b2  = (const float*)d_in[5];
    float* out = (float*)d_out;

    char* ws = (char*)d_ws;
    __bf16*         Wp   = (__bf16*)(ws + WS_WP_OFF);
    __bf16*         embp = (__bf16*)(ws + WS_EMB_OFF);
    unsigned short* x16  = (unsigned short*)(ws + WS_X16_OFF);

    prep_kernel<<<129 + 4096, 256, 0, stream>>>(x, w1, w2, emb, (uint4*)Wp, embp, x16);
    gemm_kernel<<<1024, 256, 0, stream>>>(x16, Wp, (const uint4*)embp, b1, b2, out);
}